// Round 18
// baseline (1375.643 us; speedup 1.0000x reference)
//
#include <hip/hip_runtime.h>

#define BN 262144

typedef short bf16x8 __attribute__((ext_vector_type(8)));
typedef float f32x4 __attribute__((ext_vector_type(4)));
typedef unsigned int u32x2 __attribute__((ext_vector_type(2)));

#define MFMA16(a,b,c) __builtin_amdgcn_mfma_f32_16x16x32_bf16((a),(b),(c),0,0,0)

__device__ __forceinline__ unsigned short f2bf(float f) {
  union { float f; unsigned int u; } x; x.f = f;
  unsigned int u = x.u + 0x7fffu + ((x.u >> 16) & 1u);
  return (unsigned short)(u >> 16);
}
__device__ __forceinline__ float bf2f(unsigned int h) {
  union { unsigned int u; float f; } x; x.u = h << 16;
  return x.f;
}
// pack two f32 -> (bf16_lo | bf16_hi<<16), truncating (3 VALU ops)
__device__ __forceinline__ unsigned pk2(float lo, float hi) {
  union { float f; unsigned int u; } a, b; a.f = lo; b.f = hi;
  return (a.u >> 16) | (b.u & 0xffff0000u);
}
__device__ __forceinline__ unsigned swz(int row) {
  return (((unsigned)(row & 7)) << 4) ^ (((unsigned)(row & 8)) << 2);
}

// All weight arrays in 16x16x32 fragment layout (ushort units); used as the
// MFMA *A*-operand (operand-swapped scheme): i=n=ct*16+(lane&15), k=s*32+(lane>>4)*8+j
#define O_R1 0        // W1^T: [k][n]=W1[n*64+k]   K=64  N=256 KS=2
#define O_R2 16384    // W2^T: [k][n]=W2[n*256+k]  K=256 N=256 KS=8
#define O_R3 81920    // W3^T: [k][n]=W3[n*256+k]  K=256 N=64  KS=8
#define O_R4 98304    // W3  : [k][n]=W3[k*256+n]  K=64  N=256 KS=2
#define O_R5 114688   // W2  : [k][n]=W2[k*256+n]  K=256 N=256 KS=8
#define O_R6 180224   // W1  : [k][n]=W1[k*64+n]   K=256 N=64  KS=8
#define N_WS 196608

__global__ void invres_prep(const float* __restrict__ W1, const float* __restrict__ W2,
                            const float* __restrict__ W3, unsigned short* __restrict__ wsb) {
  int idx = blockIdx.x * 256 + threadIdx.x;
  if (idx >= N_WS) return;
  int j = idx & 7;
  int lane = (idx >> 3) & 63;
  int nn = lane & 15, kn = (lane >> 4) * 8 + j;
  float val;
  if (idx < O_R2) {                // R1, KS=2
    int g = idx >> 9; int s = g & 1; int ct = g >> 1;
    val = W1[(ct * 16 + nn) * 64 + (s * 32 + kn)];
  } else if (idx < O_R3) {         // R2, KS=8
    int g = (idx - O_R2) >> 9; int s = g & 7; int ct = g >> 3;
    val = W2[(ct * 16 + nn) * 256 + (s * 32 + kn)];
  } else if (idx < O_R4) {         // R3, KS=8
    int g = (idx - O_R3) >> 9; int s = g & 7; int ct = g >> 3;
    val = W3[(ct * 16 + nn) * 256 + (s * 32 + kn)];
  } else if (idx < O_R5) {         // R4, KS=2
    int g = (idx - O_R4) >> 9; int s = g & 1; int ct = g >> 1;
    val = W3[(s * 32 + kn) * 256 + (ct * 16 + nn)];
  } else if (idx < O_R6) {         // R5, KS=8
    int g = (idx - O_R5) >> 9; int s = g & 7; int ct = g >> 3;
    val = W2[(s * 32 + kn) * 256 + (ct * 16 + nn)];
  } else {                         // R6, KS=8
    int g = (idx - O_R6) >> 9; int s = g & 7; int ct = g >> 3;
    val = W1[(s * 32 + kn) * 64 + (ct * 16 + nn)];
  }
  wsb[idx] = f2bf(val);
}

// LDS (per block, M=32), masks in registers:
//  PA 32x256 bf16 swz (16K): h1 then u2        PB (16K): h2 then u1
//  WB 32x64  bf16 swz (4K) : w
//  LDP f32[32][4] (512B)                       total 36.9K -> 3 blocks/CU
#define L_PB  16384
#define L_WB  32768
#define L_LDP 36864
#define L_SIZE 37376

__global__ void __launch_bounds__(512, 6)
invres_main(const float* __restrict__ y, const float* __restrict__ ldj,
            const float* __restrict__ v, const float* __restrict__ b1,
            const float* __restrict__ b2, const float* __restrict__ b3,
            const unsigned short* __restrict__ wsb, float* __restrict__ out) {
  extern __shared__ char smem[];
  char* PA = smem;
  char* PB = smem + L_PB;
  char* WB = smem + L_WB;
  float* ldp = (float*)(smem + L_LDP);

  const int tid = threadIdx.x;
  const int lane = tid & 63;
  const int wid = tid >> 6;          // 0..7
  const int l15 = lane & 15, g16 = lane >> 4;
  const int ct0 = wid * 2;           // wide: col tiles ct0, ct0+1 (32 cols)
  const int mh = wid >> 2;           // narrow: row half (16 rows)
  const int ctn = wid & 3;           // narrow: col tile (16 cols)
  const int r0 = blockIdx.x * 32;

  const bf16x8* R1 = (const bf16x8*)(wsb + O_R1);
  const bf16x8* R2 = (const bf16x8*)(wsb + O_R2);
  const bf16x8* R3 = (const bf16x8*)(wsb + O_R3);
  const bf16x8* R4 = (const bf16x8*)(wsb + O_R4);
  const bf16x8* R5 = (const bf16x8*)(wsb + O_R5);
  const bf16x8* R6 = (const bf16x8*)(wsb + O_R6);

  // Activation fragment (MFMA B-operand: j=row=l15, k-bundle g16) from swz LDS
  auto ldsA = [&](const char* buf, int mm, int s) -> bf16x8 {
    int row = mm * 16 + l15;
    unsigned byte = ((unsigned)(s * 64 + g16 * 16)) ^ swz(row);
    return *(const bf16x8*)(buf + row * 512 + byte);
  };
  // swapped-D epilogue store: lane holds 4 consecutive cols of row mm*16+l15 -> one b64
  auto stage64 = [&](char* buf, int mm, int cc, const float* hv) {
    int row = mm * 16 + l15;
    unsigned byte = ((unsigned)(((ct0 + cc) * 16 + g16 * 4) * 2)) ^ swz(row);
    u32x2 w; w[0] = pk2(hv[0], hv[1]); w[1] = pk2(hv[2], hv[3]);
    *(u32x2*)(buf + row * 512 + byte) = w;
  };
  // global activation fragment from y/v (row-major fp32), NT
  auto gA = [&](const float* p, int mm, int s, bool elu) -> bf16x8 {
    const float* q = p + (size_t)(r0 + mm * 16 + l15) * 64 + s * 32 + g16 * 8;
    f32x4 a = __builtin_nontemporal_load((const f32x4*)q);
    f32x4 b = __builtin_nontemporal_load((const f32x4*)(q + 4));
    float xv[8] = {a[0], a[1], a[2], a[3], b[0], b[1], b[2], b[3]};
    bf16x8 f;
#pragma unroll
    for (int i = 0; i < 8; i++) {
      float x = xv[i];
      if (elu) x = x > 0.f ? x : (__expf(x) - 1.f);
      f[i] = (short)f2bf(x);
    }
    return f;
  };

  unsigned d1p[8], d2p[8], d0p[2], v0p[2];
  float ldacc[4] = {0.f, 0.f, 0.f, 0.f};

  // ---------------- G1: h1 = elu(elu(y) @ W1^T + b1) -> PA ; d1 -> regs ----------------
  {
    f32x4 bv1[2];
#pragma unroll
    for (int cc = 0; cc < 2; cc++) bv1[cc] = *(const f32x4*)(b1 + (ct0 + cc) * 16 + g16 * 4);
    f32x4 acc[2][2] = {};
#pragma unroll
    for (int s = 0; s < 2; s++) {
      bf16x8 a0 = gA(y, 0, s, true);
      bf16x8 a1 = gA(y, 1, s, true);
#pragma unroll
      for (int cc = 0; cc < 2; cc++) {
        bf16x8 B = R1[((ct0 + cc) * 2 + s) * 64 + lane];
        acc[0][cc] = MFMA16(B, a0, acc[0][cc]);
        acc[1][cc] = MFMA16(B, a1, acc[1][cc]);
      }
    }
#pragma unroll
    for (int mm = 0; mm < 2; mm++)
#pragma unroll
      for (int cc = 0; cc < 2; cc++) {
        float hv[4], dv[4];
#pragma unroll
        for (int r = 0; r < 4; r++) {
          float a = acc[mm][cc][r] + bv1[cc][r];
          float e = __expf(a);
          hv[r] = a > 0.f ? a : (e - 1.f);
          dv[r] = a > 0.f ? 1.f : e;
        }
        stage64(PA, mm, cc, hv);
        int base = (mm * 2 + cc) * 2;
        d1p[base] = pk2(dv[0], dv[1]);
        d1p[base + 1] = pk2(dv[2], dv[3]);
      }
  }
  __syncthreads();

  // ---------------- G2: h2 = elu(h1 @ W2^T + b2) -> PB ; d2 -> regs ----------------
  {
    f32x4 acc[2][2] = {};
#pragma unroll 1
    for (int s = 0; s < 8; s++) {
      bf16x8 a0 = ldsA(PA, 0, s);
      bf16x8 a1 = ldsA(PA, 1, s);
      bf16x8 B0 = R2[(ct0 * 8 + s) * 64 + lane];
      bf16x8 B1 = R2[((ct0 + 1) * 8 + s) * 64 + lane];
      acc[0][0] = MFMA16(B0, a0, acc[0][0]);
      acc[0][1] = MFMA16(B1, a0, acc[0][1]);
      acc[1][0] = MFMA16(B0, a1, acc[1][0]);
      acc[1][1] = MFMA16(B1, a1, acc[1][1]);
    }
    f32x4 bv2[2];
#pragma unroll
    for (int cc = 0; cc < 2; cc++) bv2[cc] = *(const f32x4*)(b2 + (ct0 + cc) * 16 + g16 * 4);
#pragma unroll
    for (int mm = 0; mm < 2; mm++)
#pragma unroll
      for (int cc = 0; cc < 2; cc++) {
        float hv[4], dv[4];
#pragma unroll
        for (int r = 0; r < 4; r++) {
          float a = acc[mm][cc][r] + bv2[cc][r];
          float e = __expf(a);
          hv[r] = a > 0.f ? a : (e - 1.f);
          dv[r] = a > 0.f ? 1.f : e;
        }
        stage64(PB, mm, cc, hv);
        int base = (mm * 2 + cc) * 2;
        d2p[base] = pk2(dv[0], dv[1]);
        d2p[base + 1] = pk2(dv[2], dv[3]);
      }
  }
  __syncthreads();

  // ---------------- G3: z = y + h2 @ W3^T + b3 ; d0, v0 ----------------
  {
    f32x4 acc0 = {}, acc1 = {};
#pragma unroll 1
    for (int s = 0; s < 8; s += 2) {
      acc0 = MFMA16(R3[(ctn * 8 + s) * 64 + lane], ldsA(PB, mh, s), acc0);
      acc1 = MFMA16(R3[(ctn * 8 + s + 1) * 64 + lane], ldsA(PB, mh, s + 1), acc1);
    }
    f32x4 bv3 = *(const f32x4*)(b3 + ctn * 16 + g16 * 4);
    int row = r0 + mh * 16 + l15;
    int col = ctn * 16 + g16 * 4;
    size_t off = (size_t)row * 64 + col;
    f32x4 yv = __builtin_nontemporal_load((const f32x4*)(y + off));
    f32x4 vv = __builtin_nontemporal_load((const f32x4*)(v + off));
    f32x4 zv;
    float d0v[4];
#pragma unroll
    for (int r = 0; r < 4; r++) {
      zv[r] = yv[r] + acc0[r] + acc1[r] + bv3[r];
      d0v[r] = yv[r] > 0.f ? 1.f : __expf(yv[r]);
    }
    __builtin_nontemporal_store(zv, (f32x4*)(out + off));
    d0p[0] = pk2(d0v[0], d0v[1]); d0p[1] = pk2(d0v[2], d0v[3]);
    v0p[0] = pk2(vv[0], vv[1]);   v0p[1] = pk2(vv[2], vv[3]);
  }

  // ---------------- G4 (k=1): u2 = (v0 @ W3) * d2 -> PA ----------------
  {
    f32x4 acc[2][2] = {};
#pragma unroll
    for (int s = 0; s < 2; s++) {
      bf16x8 a0 = gA(v, 0, s, false);
      bf16x8 a1 = gA(v, 1, s, false);
#pragma unroll
      for (int cc = 0; cc < 2; cc++) {
        bf16x8 B = R4[((ct0 + cc) * 2 + s) * 64 + lane];
        acc[0][cc] = MFMA16(B, a0, acc[0][cc]);
        acc[1][cc] = MFMA16(B, a1, acc[1][cc]);
      }
    }
#pragma unroll
    for (int mm = 0; mm < 2; mm++)
#pragma unroll
      for (int cc = 0; cc < 2; cc++) {
        int base = (mm * 2 + cc) * 2;
        float uv[4];
#pragma unroll
        for (int r = 0; r < 4; r++)
          uv[r] = acc[mm][cc][r] * bf2f((d2p[base + (r >> 1)] >> ((r & 1) * 16)) & 0xffffu);
        stage64(PA, mm, cc, uv);
      }
  }
  __syncthreads();

  // ---------------- backward iterations ----------------
  for (int k = 1; k <= 8; ++k) {
    // G5: u1 = (u2 @ W2) * d1 -> PB
    {
      f32x4 acc[2][2] = {};
#pragma unroll 1
      for (int s = 0; s < 8; s++) {
        bf16x8 a0 = ldsA(PA, 0, s);
        bf16x8 a1 = ldsA(PA, 1, s);
        bf16x8 B0 = R5[(ct0 * 8 + s) * 64 + lane];
        bf16x8 B1 = R5[((ct0 + 1) * 8 + s) * 64 + lane];
        acc[0][0] = MFMA16(B0, a0, acc[0][0]);
        acc[0][1] = MFMA16(B1, a0, acc[0][1]);
        acc[1][0] = MFMA16(B0, a1, acc[1][0]);
        acc[1][1] = MFMA16(B1, a1, acc[1][1]);
      }
#pragma unroll
      for (int mm = 0; mm < 2; mm++)
#pragma unroll
        for (int cc = 0; cc < 2; cc++) {
          int base = (mm * 2 + cc) * 2;
          float uv[4];
#pragma unroll
          for (int r = 0; r < 4; r++)
            uv[r] = acc[mm][cc][r] * bf2f((d1p[base + (r >> 1)] >> ((r & 1) * 16)) & 0xffffu);
          stage64(PB, mm, cc, uv);
        }
    }
    __syncthreads();

    // G6: w' = (u1 @ W1) * d0 ; log-det ; w' -> WB
    {
      float coef = (k & 1) ? (1.f / (float)k) : (-1.f / (float)k);
      f32x4 acc0 = {}, acc1 = {};
#pragma unroll 1
      for (int s = 0; s < 8; s += 2) {
        acc0 = MFMA16(R6[(ctn * 8 + s) * 64 + lane], ldsA(PB, mh, s), acc0);
        acc1 = MFMA16(R6[(ctn * 8 + s + 1) * 64 + lane], ldsA(PB, mh, s + 1), acc1);
      }
      float wv[4];
#pragma unroll
      for (int r = 0; r < 4; r++) {
        wv[r] = (acc0[r] + acc1[r]) * bf2f((d0p[r >> 1] >> ((r & 1) * 16)) & 0xffffu);
        ldacc[r] += coef * wv[r] * bf2f((v0p[r >> 1] >> ((r & 1) * 16)) & 0xffffu);
      }
      if (k < 8) {
        int row = mh * 16 + l15;
        unsigned byte = ((unsigned)((ctn * 16 + g16 * 4) * 2)) ^ swz(row);
        u32x2 w; w[0] = pk2(wv[0], wv[1]); w[1] = pk2(wv[2], wv[3]);
        *(u32x2*)(WB + row * 128 + byte) = w;
      }
    }
    if (k < 8) {
      __syncthreads();
      // G4': u2 = (w' @ W3) * d2 -> PA
      f32x4 acc[2][2] = {};
#pragma unroll
      for (int s = 0; s < 2; s++) {
        bf16x8 a0, a1;
#pragma unroll
        for (int mm = 0; mm < 2; mm++) {
          int row = mm * 16 + l15;
          unsigned byte = ((unsigned)(s * 64 + g16 * 16)) ^ swz(row);
          bf16x8 a = *(const bf16x8*)(WB + row * 128 + byte);
          if (mm == 0) a0 = a; else a1 = a;
        }
#pragma unroll
        for (int cc = 0; cc < 2; cc++) {
          bf16x8 B = R4[((ct0 + cc) * 2 + s) * 64 + lane];
          acc[0][cc] = MFMA16(B, a0, acc[0][cc]);
          acc[1][cc] = MFMA16(B, a1, acc[1][cc]);
        }
      }
#pragma unroll
      for (int mm = 0; mm < 2; mm++)
#pragma unroll
        for (int cc = 0; cc < 2; cc++) {
          int base = (mm * 2 + cc) * 2;
          float uv[4];
#pragma unroll
          for (int r = 0; r < 4; r++)
            uv[r] = acc[mm][cc][r] * bf2f((d2p[base + (r >> 1)] >> ((r & 1) * 16)) & 0xffffu);
          stage64(PA, mm, cc, uv);
        }
      __syncthreads();
    }
  }

  // ---------------- log-det epilogue ----------------
  {
    float s = ldacc[0] + ldacc[1] + ldacc[2] + ldacc[3];
    s += __shfl_xor(s, 16);
    s += __shfl_xor(s, 32);
    if (g16 == 0) ldp[(mh * 16 + l15) * 4 + ctn] = s;
  }
  __syncthreads();
  if (tid < 32) {
    float s = ldp[tid * 4] + ldp[tid * 4 + 1] + ldp[tid * 4 + 2] + ldp[tid * 4 + 3];
    int gb = r0 + tid;
    __builtin_nontemporal_store(ldj[gb] + s, out + (size_t)BN * 64 + gb);
  }
}

extern "C" void kernel_launch(void* const* d_in, const int* in_sizes, int n_in,
                              void* d_out, int out_size, void* d_ws, size_t ws_size,
                              hipStream_t stream) {
  const float* y   = (const float*)d_in[0];
  const float* ldj = (const float*)d_in[1];
  const float* v   = (const float*)d_in[2];
  const float* W1  = (const float*)d_in[3];
  const float* b1  = (const float*)d_in[4];
  const float* W2  = (const float*)d_in[5];
  const float* b2  = (const float*)d_in[6];
  const float* W3  = (const float*)d_in[7];
  const float* b3  = (const float*)d_in[8];
  unsigned short* wsb = (unsigned short*)d_ws;
  float* out = (float*)d_out;

  (void)hipFuncSetAttribute(reinterpret_cast<const void*>(&invres_main),
                            hipFuncAttributeMaxDynamicSharedMemorySize, L_SIZE);

  invres_prep<<<N_WS / 256, 256, 0, stream>>>(W1, W2, W3, wsb);
  invres_main<<<BN / 32, 512, L_SIZE, stream>>>(y, ldj, v, b1, b2, b3, wsb, out);
}

// Round 20
// 766.483 us; speedup vs baseline: 1.7947x; 1.7947x over previous
//
#include <hip/hip_runtime.h>

#define BN 262144

typedef short bf16x8 __attribute__((ext_vector_type(8)));
typedef float f32x4 __attribute__((ext_vector_type(4)));
typedef unsigned int u32x2 __attribute__((ext_vector_type(2)));

#define MFMA16(a,b,c) __builtin_amdgcn_mfma_f32_16x16x32_bf16((a),(b),(c),0,0,0)

__device__ __forceinline__ unsigned short f2bf(float f) {
  union { float f; unsigned int u; } x; x.f = f;
  unsigned int u = x.u + 0x7fffu + ((x.u >> 16) & 1u);
  return (unsigned short)(u >> 16);
}
__device__ __forceinline__ float bf2f(unsigned int h) {
  union { unsigned int u; float f; } x; x.u = h << 16;
  return x.f;
}
// pack two f32 -> (bf16_lo | bf16_hi<<16), truncating (3 VALU ops) — proven path
__device__ __forceinline__ unsigned pk2(float lo, float hi) {
  union { float f; unsigned int u; } a, b; a.f = lo; b.f = hi;
  return (a.u >> 16) | (b.u & 0xffff0000u);
}
__device__ __forceinline__ unsigned swz(int row) {
  return (((unsigned)(row & 7)) << 4) ^ (((unsigned)(row & 8)) << 2);
}

// All weight arrays in 16x16x32 fragment layout (ushort units); used as the
// MFMA *A*-operand (operand-swapped scheme): i=n=ct*16+(lane&15), k=s*32+(lane>>4)*8+j
#define O_R1 0        // W1^T: [k][n]=W1[n*64+k]   K=64  N=256 KS=2
#define O_R2 16384    // W2^T: [k][n]=W2[n*256+k]  K=256 N=256 KS=8
#define O_R3 81920    // W3^T: [k][n]=W3[n*256+k]  K=256 N=64  KS=8
#define O_R4 98304    // W3  : [k][n]=W3[k*256+n]  K=64  N=256 KS=2
#define O_R5 114688   // W2  : [k][n]=W2[k*256+n]  K=256 N=256 KS=8
#define O_R6 180224   // W1  : [k][n]=W1[k*64+n]   K=256 N=64  KS=8
#define N_WS 196608

__global__ void invres_prep(const float* __restrict__ W1, const float* __restrict__ W2,
                            const float* __restrict__ W3, unsigned short* __restrict__ wsb) {
  int idx = blockIdx.x * 256 + threadIdx.x;
  if (idx >= N_WS) return;
  int j = idx & 7;
  int lane = (idx >> 3) & 63;
  int nn = lane & 15, kn = (lane >> 4) * 8 + j;
  float val;
  if (idx < O_R2) {                // R1, KS=2
    int g = idx >> 9; int s = g & 1; int ct = g >> 1;
    val = W1[(ct * 16 + nn) * 64 + (s * 32 + kn)];
  } else if (idx < O_R3) {         // R2, KS=8
    int g = (idx - O_R2) >> 9; int s = g & 7; int ct = g >> 3;
    val = W2[(ct * 16 + nn) * 256 + (s * 32 + kn)];
  } else if (idx < O_R4) {         // R3, KS=8
    int g = (idx - O_R3) >> 9; int s = g & 7; int ct = g >> 3;
    val = W3[(ct * 16 + nn) * 256 + (s * 32 + kn)];
  } else if (idx < O_R5) {         // R4, KS=2
    int g = (idx - O_R4) >> 9; int s = g & 1; int ct = g >> 1;
    val = W3[(s * 32 + kn) * 256 + (ct * 16 + nn)];
  } else if (idx < O_R6) {         // R5, KS=8
    int g = (idx - O_R5) >> 9; int s = g & 7; int ct = g >> 3;
    val = W2[(s * 32 + kn) * 256 + (ct * 16 + nn)];
  } else {                         // R6, KS=8
    int g = (idx - O_R6) >> 9; int s = g & 7; int ct = g >> 3;
    val = W1[(s * 32 + kn) * 64 + (ct * 16 + nn)];
  }
  wsb[idx] = f2bf(val);
}

// LDS (per block, M=32), SINGLE staging buffer P time-shared (h1->h2->u2/u1):
//  P  32x256 bf16 swz (16K)
//  WB 32x64  bf16 swz (4K)
//  D1/D2 (16K each): elu' masks, thread-private b64 granules [wid][mc][lane]
//  LDP f32[32][4] (512B)                                total 52.5K -> 3 blocks/CU
#define L_WB  16384
#define L_D1  20480
#define L_D2  36864
#define L_LDP 53248
#define L_SIZE 53760

__global__ void __launch_bounds__(512, 6)
invres_main(const float* __restrict__ y, const float* __restrict__ ldj,
            const float* __restrict__ v, const float* __restrict__ b1,
            const float* __restrict__ b2, const float* __restrict__ b3,
            const unsigned short* __restrict__ wsb, float* __restrict__ out) {
  extern __shared__ char smem[];
  char* P  = smem;
  char* WB = smem + L_WB;
  char* D1 = smem + L_D1;
  char* D2 = smem + L_D2;
  float* ldp = (float*)(smem + L_LDP);

  const int tid = threadIdx.x;
  const int lane = tid & 63;
  const int wid = tid >> 6;          // 0..7
  const int l15 = lane & 15, g16 = lane >> 4;
  const int ct0 = wid * 2;           // wide: col tiles ct0, ct0+1 (32 cols)
  const int mh = wid >> 2;           // narrow: row half (16 rows)
  const int ctn = wid & 3;           // narrow: col tile (16 cols)
  const int r0 = blockIdx.x * 32;

  const bf16x8* R1 = (const bf16x8*)(wsb + O_R1);
  const bf16x8* R2 = (const bf16x8*)(wsb + O_R2);
  const bf16x8* R3 = (const bf16x8*)(wsb + O_R3);
  const bf16x8* R4 = (const bf16x8*)(wsb + O_R4);
  const bf16x8* R5 = (const bf16x8*)(wsb + O_R5);
  const bf16x8* R6 = (const bf16x8*)(wsb + O_R6);

  // mask granule byte offset (thread-private slot): [wid][mc][lane] x 8B
  auto mOff = [&](int mc) -> int { return ((wid * 4 + mc) * 64 + lane) * 8; };

  // Activation fragment (MFMA B-operand: j=row=l15, k-bundle g16) from swz LDS
  auto ldsA = [&](const char* buf, int mm, int s) -> bf16x8 {
    int row = mm * 16 + l15;
    unsigned byte = ((unsigned)(s * 64 + g16 * 16)) ^ swz(row);
    return *(const bf16x8*)(buf + row * 512 + byte);
  };
  // swapped-D epilogue store: lane holds 4 consecutive cols of row mm*16+l15 -> one b64
  auto stage64 = [&](char* buf, int mm, int cc, const float* hv) {
    int row = mm * 16 + l15;
    unsigned byte = ((unsigned)(((ct0 + cc) * 16 + g16 * 4) * 2)) ^ swz(row);
    u32x2 w; w[0] = pk2(hv[0], hv[1]); w[1] = pk2(hv[2], hv[3]);
    *(u32x2*)(buf + row * 512 + byte) = w;
  };
  // global activation fragment from y/v (row-major fp32), NT
  auto gA = [&](const float* p, int mm, int s, bool elu) -> bf16x8 {
    const float* q = p + (size_t)(r0 + mm * 16 + l15) * 64 + s * 32 + g16 * 8;
    f32x4 a = __builtin_nontemporal_load((const f32x4*)q);
    f32x4 b = __builtin_nontemporal_load((const f32x4*)(q + 4));
    float xv[8] = {a[0], a[1], a[2], a[3], b[0], b[1], b[2], b[3]};
    bf16x8 f;
#pragma unroll
    for (int i = 0; i < 8; i++) {
      float x = xv[i];
      if (elu) x = x > 0.f ? x : (__expf(x) - 1.f);
      f[i] = (short)f2bf(x);
    }
    return f;
  };

  unsigned d0p[2], v0p[2];
  float ldacc[4] = {0.f, 0.f, 0.f, 0.f};

  // ---------------- G1: h1 = elu(elu(y) @ W1^T + b1) -> P ; d1 -> D1 ----------------
  {
    f32x4 bv1[2];
#pragma unroll
    for (int cc = 0; cc < 2; cc++) bv1[cc] = *(const f32x4*)(b1 + (ct0 + cc) * 16 + g16 * 4);
    f32x4 acc[2][2] = {};
    __builtin_amdgcn_s_setprio(1);
#pragma unroll
    for (int s = 0; s < 2; s++) {
      bf16x8 a0 = gA(y, 0, s, true);
      bf16x8 a1 = gA(y, 1, s, true);
#pragma unroll
      for (int cc = 0; cc < 2; cc++) {
        bf16x8 B = R1[((ct0 + cc) * 2 + s) * 64 + lane];
        acc[0][cc] = MFMA16(B, a0, acc[0][cc]);
        acc[1][cc] = MFMA16(B, a1, acc[1][cc]);
      }
    }
    __builtin_amdgcn_s_setprio(0);
#pragma unroll
    for (int mm = 0; mm < 2; mm++)
#pragma unroll
      for (int cc = 0; cc < 2; cc++) {
        float hv[4], dv[4];
#pragma unroll
        for (int r = 0; r < 4; r++) {
          float a = acc[mm][cc][r] + bv1[cc][r];
          float e = __expf(a);
          hv[r] = a > 0.f ? a : (e - 1.f);
          dv[r] = a > 0.f ? 1.f : e;
        }
        stage64(P, mm, cc, hv);
        u32x2 w; w[0] = pk2(dv[0], dv[1]); w[1] = pk2(dv[2], dv[3]);
        *(u32x2*)(D1 + mOff(mm * 2 + cc)) = w;
      }
  }
  __syncthreads();

  // ---------------- G2: h2 = elu(h1 @ W2^T + b2) -> P (split) ; d2 -> D2 ----------------
  {
    f32x4 acc[2][2] = {};
    __builtin_amdgcn_s_setprio(1);
#pragma unroll 1
    for (int s = 0; s < 8; s++) {
      bf16x8 a0 = ldsA(P, 0, s);
      bf16x8 a1 = ldsA(P, 1, s);
      bf16x8 B0 = R2[(ct0 * 8 + s) * 64 + lane];
      bf16x8 B1 = R2[((ct0 + 1) * 8 + s) * 64 + lane];
      acc[0][0] = MFMA16(B0, a0, acc[0][0]);
      acc[0][1] = MFMA16(B1, a0, acc[0][1]);
      acc[1][0] = MFMA16(B0, a1, acc[1][0]);
      acc[1][1] = MFMA16(B1, a1, acc[1][1]);
    }
    __builtin_amdgcn_s_setprio(0);
    __syncthreads();   // all h1 reads done before overwrite
    f32x4 bv2[2];
#pragma unroll
    for (int cc = 0; cc < 2; cc++) bv2[cc] = *(const f32x4*)(b2 + (ct0 + cc) * 16 + g16 * 4);
#pragma unroll
    for (int mm = 0; mm < 2; mm++)
#pragma unroll
      for (int cc = 0; cc < 2; cc++) {
        float hv[4], dv[4];
#pragma unroll
        for (int r = 0; r < 4; r++) {
          float a = acc[mm][cc][r] + bv2[cc][r];
          float e = __expf(a);
          hv[r] = a > 0.f ? a : (e - 1.f);
          dv[r] = a > 0.f ? 1.f : e;
        }
        stage64(P, mm, cc, hv);
        u32x2 w; w[0] = pk2(dv[0], dv[1]); w[1] = pk2(dv[2], dv[3]);
        *(u32x2*)(D2 + mOff(mm * 2 + cc)) = w;
      }
  }
  __syncthreads();

  // ---------------- G3: z = y + h2 @ W3^T + b3 ; d0, v0 ----------------
  {
    f32x4 acc0 = {}, acc1 = {};
    __builtin_amdgcn_s_setprio(1);
#pragma unroll 1
    for (int s = 0; s < 8; s += 2) {
      acc0 = MFMA16(R3[(ctn * 8 + s) * 64 + lane], ldsA(P, mh, s), acc0);
      acc1 = MFMA16(R3[(ctn * 8 + s + 1) * 64 + lane], ldsA(P, mh, s + 1), acc1);
    }
    __builtin_amdgcn_s_setprio(0);
    f32x4 bv3 = *(const f32x4*)(b3 + ctn * 16 + g16 * 4);
    int row = r0 + mh * 16 + l15;
    int col = ctn * 16 + g16 * 4;
    size_t off = (size_t)row * 64 + col;
    f32x4 yv = __builtin_nontemporal_load((const f32x4*)(y + off));
    f32x4 vv = __builtin_nontemporal_load((const f32x4*)(v + off));
    f32x4 zv;
    float d0v[4];
#pragma unroll
    for (int r = 0; r < 4; r++) {
      zv[r] = yv[r] + acc0[r] + acc1[r] + bv3[r];
      d0v[r] = yv[r] > 0.f ? 1.f : __expf(yv[r]);
    }
    __builtin_nontemporal_store(zv, (f32x4*)(out + off));
    d0p[0] = pk2(d0v[0], d0v[1]); d0p[1] = pk2(d0v[2], d0v[3]);
    v0p[0] = pk2(vv[0], vv[1]);   v0p[1] = pk2(vv[2], vv[3]);
  }
  __syncthreads();   // h2 reads done before u2 overwrites P

  // ---------------- G4 (k=1): u2 = (v0 @ W3) * d2 -> P ----------------
  {
    f32x4 acc[2][2] = {};
    __builtin_amdgcn_s_setprio(1);
#pragma unroll
    for (int s = 0; s < 2; s++) {
      bf16x8 a0 = gA(v, 0, s, false);
      bf16x8 a1 = gA(v, 1, s, false);
#pragma unroll
      for (int cc = 0; cc < 2; cc++) {
        bf16x8 B = R4[((ct0 + cc) * 2 + s) * 64 + lane];
        acc[0][cc] = MFMA16(B, a0, acc[0][cc]);
        acc[1][cc] = MFMA16(B, a1, acc[1][cc]);
      }
    }
    __builtin_amdgcn_s_setprio(0);
#pragma unroll
    for (int mm = 0; mm < 2; mm++)
#pragma unroll
      for (int cc = 0; cc < 2; cc++) {
        u32x2 dd = *(const u32x2*)(D2 + mOff(mm * 2 + cc));
        float uv[4];
#pragma unroll
        for (int r = 0; r < 4; r++)
          uv[r] = acc[mm][cc][r] * bf2f((dd[r >> 1] >> ((r & 1) * 16)) & 0xffffu);
        stage64(P, mm, cc, uv);
      }
  }
  __syncthreads();

  // ---------------- backward iterations ----------------
  for (int k = 1; k <= 8; ++k) {
    // G5: u1 = (u2 @ W2) * d1 -> P (split read|write)
    {
      f32x4 acc[2][2] = {};
      __builtin_amdgcn_s_setprio(1);
#pragma unroll 1
      for (int s = 0; s < 8; s++) {
        bf16x8 a0 = ldsA(P, 0, s);
        bf16x8 a1 = ldsA(P, 1, s);
        bf16x8 B0 = R5[(ct0 * 8 + s) * 64 + lane];
        bf16x8 B1 = R5[((ct0 + 1) * 8 + s) * 64 + lane];
        acc[0][0] = MFMA16(B0, a0, acc[0][0]);
        acc[0][1] = MFMA16(B1, a0, acc[0][1]);
        acc[1][0] = MFMA16(B0, a1, acc[1][0]);
        acc[1][1] = MFMA16(B1, a1, acc[1][1]);
      }
      __builtin_amdgcn_s_setprio(0);
      __syncthreads();   // all u2 reads done
#pragma unroll
      for (int mm = 0; mm < 2; mm++)
#pragma unroll
        for (int cc = 0; cc < 2; cc++) {
          u32x2 dd = *(const u32x2*)(D1 + mOff(mm * 2 + cc));
          float uv[4];
#pragma unroll
          for (int r = 0; r < 4; r++)
            uv[r] = acc[mm][cc][r] * bf2f((dd[r >> 1] >> ((r & 1) * 16)) & 0xffffu);
          stage64(P, mm, cc, uv);
        }
    }
    __syncthreads();

    // G6: w' = (u1 @ W1) * d0 ; log-det ; w' -> WB
    {
      float coef = (k & 1) ? (1.f / (float)k) : (-1.f / (float)k);
      f32x4 acc0 = {}, acc1 = {};
      __builtin_amdgcn_s_setprio(1);
#pragma unroll 1
      for (int s = 0; s < 8; s += 2) {
        acc0 = MFMA16(R6[(ctn * 8 + s) * 64 + lane], ldsA(P, mh, s), acc0);
        acc1 = MFMA16(R6[(ctn * 8 + s + 1) * 64 + lane], ldsA(P, mh, s + 1), acc1);
      }
      __builtin_amdgcn_s_setprio(0);
      float wv[4];
#pragma unroll
      for (int r = 0; r < 4; r++) {
        wv[r] = (acc0[r] + acc1[r]) * bf2f((d0p[r >> 1] >> ((r & 1) * 16)) & 0xffffu);
        ldacc[r] += coef * wv[r] * bf2f((v0p[r >> 1] >> ((r & 1) * 16)) & 0xffffu);
      }
      if (k < 8) {
        int row = mh * 16 + l15;
        unsigned byte = ((unsigned)((ctn * 16 + g16 * 4) * 2)) ^ swz(row);
        u32x2 w; w[0] = pk2(wv[0], wv[1]); w[1] = pk2(wv[2], wv[3]);
        *(u32x2*)(WB + row * 128 + byte) = w;
      }
    }
    if (k < 8) {
      __syncthreads();   // WB written, u1 reads done
      // G4': u2 = (w' @ W3) * d2 -> P
      f32x4 acc[2][2] = {};
      __builtin_amdgcn_s_setprio(1);
#pragma unroll
      for (int s = 0; s < 2; s++) {
        bf16x8 a0, a1;
#pragma unroll
        for (int mm = 0; mm < 2; mm++) {
          int row = mm * 16 + l15;
          unsigned byte = ((unsigned)(s * 64 + g16 * 16)) ^ swz(row);
          bf16x8 a = *(const bf16x8*)(WB + row * 128 + byte);
          if (mm == 0) a0 = a; else a1 = a;
        }
#pragma unroll
        for (int cc = 0; cc < 2; cc++) {
          bf16x8 B = R4[((ct0 + cc) * 2 + s) * 64 + lane];
          acc[0][cc] = MFMA16(B, a0, acc[0][cc]);
          acc[1][cc] = MFMA16(B, a1, acc[1][cc]);
        }
      }
      __builtin_amdgcn_s_setprio(0);
#pragma unroll
      for (int mm = 0; mm < 2; mm++)
#pragma unroll
        for (int cc = 0; cc < 2; cc++) {
          u32x2 dd = *(const u32x2*)(D2 + mOff(mm * 2 + cc));
          float uv[4];
#pragma unroll
          for (int r = 0; r < 4; r++)
            uv[r] = acc[mm][cc][r] * bf2f((dd[r >> 1] >> ((r & 1) * 16)) & 0xffffu);
          stage64(P, mm, cc, uv);
        }
      __syncthreads();
    }
  }

  // ---------------- log-det epilogue ----------------
  {
    float s = ldacc[0] + ldacc[1] + ldacc[2] + ldacc[3];
    s += __shfl_xor(s, 16);
    s += __shfl_xor(s, 32);
    if (g16 == 0) ldp[(mh * 16 + l15) * 4 + ctn] = s;
  }
  __syncthreads();
  if (tid < 32) {
    float s = ldp[tid * 4] + ldp[tid * 4 + 1] + ldp[tid * 4 + 2] + ldp[tid * 4 + 3];
    int gb = r0 + tid;
    __builtin_nontemporal_store(ldj[gb] + s, out + (size_t)BN * 64 + gb);
  }
}

extern "C" void kernel_launch(void* const* d_in, const int* in_sizes, int n_in,
                              void* d_out, int out_size, void* d_ws, size_t ws_size,
                              hipStream_t stream) {
  const float* y   = (const float*)d_in[0];
  const float* ldj = (const float*)d_in[1];
  const float* v   = (const float*)d_in[2];
  const float* W1  = (const float*)d_in[3];
  const float* b1  = (const float*)d_in[4];
  const float* W2  = (const float*)d_in[5];
  const float* b2  = (const float*)d_in[6];
  const float* W3  = (const float*)d_in[7];
  const float* b3  = (const float*)d_in[8];
  unsigned short* wsb = (unsigned short*)d_ws;
  float* out = (float*)d_out;

  (void)hipFuncSetAttribute(reinterpret_cast<const void*>(&invres_main),
                            hipFuncAttributeMaxDynamicSharedMemorySize, L_SIZE);

  invres_prep<<<N_WS / 256, 256, 0, stream>>>(W1, W2, W3, wsb);
  invres_main<<<BN / 32, 512, L_SIZE, stream>>>(y, ldj, v, b1, b2, b3, wsb, out);
}